// Round 1
// baseline (697.739 us; speedup 1.0000x reference)
//
#include <hip/hip_runtime.h>

// VQ-VAE fused forward, f32 throughout.
// Algebraic restructuring: all 512-dim contractions folded into precomputed
// 128x128 (or smaller) matrices:
//   WC[k][c]  = enc_wf[k,:]·cb[c,:]          (P = rep·cb^T = h2@WC + bfc)
//   Gm[o][k]  = enc_wf[o,:]·enc_wf[k,:]      (||rep||^2 = h2^T Gm h2 + 2 u·h2 + bb)
//   Mdec[r][j]= cb[r,:]·dec_w1[:,j]          (dec h1 preact = b1d + sum_g Mdec[g*32+k_g])
//   Gram[ga,gb,ka,kb] = cb_ga[ka,:]·cb_gb[kb,:]  (residual dots across groups)
// Residual-VQ scoring then needs only P[128] + scalars per sample.

#define SIN  90
#define HID  128
#define DLAT 512
#define NC   128   // total codes (4*32)
#define GQ   4

// ws float layout, after 8 doubles (64 bytes) of accumulators:
//   [0,16384)      WC
//   [16384,32768)  Gm
//   [32768,49152)  Mdec  (row = g*32+k, col j)
//   [49152,65536)  Gram  idx = ((ga*4+gb)*32+ka)*32+kb
//   [65536,65664)  cbn2[128]
//   [65664,65792)  u[128]      (wf·bf)
//   [65792,65920)  bfc[128]    (bf·cb_c)
//   [65920]        bb = ||bf||^2
#define PRE_N 65921

__global__ void k_zero(double* __restrict__ acc) {
    if (threadIdx.x < 4) acc[threadIdx.x] = 0.0;
}

__global__ void k_pre(const float* __restrict__ wf, const float* __restrict__ bf,
                      const float* __restrict__ w1d, const float* __restrict__ cb,
                      float* __restrict__ P) {
    int idx = blockIdx.x * 256 + threadIdx.x;
    if (idx >= PRE_N) return;
    float s = 0.f;
    if (idx < 16384) {
        int k = idx >> 7, c = idx & 127;
        const float* a = wf + k * DLAT; const float* b = cb + c * DLAT;
        for (int d = 0; d < DLAT; ++d) s = fmaf(a[d], b[d], s);
    } else if (idx < 32768) {
        int r = idx - 16384; int o = r >> 7, k = r & 127;
        const float* a = wf + o * DLAT; const float* b = wf + k * DLAT;
        for (int d = 0; d < DLAT; ++d) s = fmaf(a[d], b[d], s);
    } else if (idx < 49152) {
        int r = idx - 32768; int row = r >> 7, j = r & 127;
        const float* a = cb + row * DLAT;
        for (int d = 0; d < DLAT; ++d) s = fmaf(a[d], w1d[d * HID + j], s);
    } else if (idx < 65536) {
        int r = idx - 49152;
        int kb = r & 31, ka = (r >> 5) & 31, gb = (r >> 10) & 3, ga = (r >> 12) & 3;
        const float* a = cb + (ga * 32 + ka) * DLAT;
        const float* b = cb + (gb * 32 + kb) * DLAT;
        for (int d = 0; d < DLAT; ++d) s = fmaf(a[d], b[d], s);
    } else if (idx < 65664) {
        int c = idx - 65536;
        const float* a = cb + c * DLAT;
        for (int d = 0; d < DLAT; ++d) s = fmaf(a[d], a[d], s);
    } else if (idx < 65792) {
        int k = idx - 65664;
        const float* a = wf + k * DLAT;
        for (int d = 0; d < DLAT; ++d) s = fmaf(a[d], bf[d], s);
    } else if (idx < 65920) {
        int c = idx - 65792;
        const float* a = cb + c * DLAT;
        for (int d = 0; d < DLAT; ++d) s = fmaf(bf[d], a[d], s);
    } else {
        for (int d = 0; d < DLAT; ++d) s = fmaf(bf[d], bf[d], s);
    }
    P[idx] = s;
}

__global__ __launch_bounds__(256, 2) void k_main(
    const float* __restrict__ x,
    const float* __restrict__ w1, const float* __restrict__ b1,
    const float* __restrict__ w2, const float* __restrict__ b2,
    const float* __restrict__ b1d,
    const float* __restrict__ w2d, const float* __restrict__ b2d,
    const float* __restrict__ wfd, const float* __restrict__ bfd,
    const float* __restrict__ pre,
    float* __restrict__ out, double* __restrict__ acc, int Bn)
{
    __shared__ float Abuf[HID * 64];
    __shared__ float Bbuf[HID * 64];
    __shared__ float qfb[4 * 64];
    __shared__ int   cbuf[4 * 64];
    __shared__ float red[8];

    const int t = threadIdx.x;
    const int lane = t & 63;
    const int wv = t >> 6;
    const int ob = __builtin_amdgcn_readfirstlane(wv) * 32;   // wave-uniform out-chunk base
    const long s_glob = (long)blockIdx.x * 64 + lane;

    const float* WC   = pre;
    const float* Gm   = pre + 16384;
    const float* Mdec = pre + 32768;
    const float* Gram = pre + 49152;
    const float* cbn2 = pre + 65536;
    const float* uu   = pre + 65664;
    const float* bfc  = pre + 65792;
    const float  bb   = pre[65920];

    float a[32];

    // ---- P1: enc h1 = relu(x@w1 + b1) -> Abuf[dim][64]
    #pragma unroll
    for (int i = 0; i < 32; ++i) a[i] = b1[ob + i];
    {
        const float* xr = x + s_glob * SIN;
        for (int k = 0; k < SIN; ++k) {
            float v = xr[k];
            const float* wr = w1 + k * HID + ob;
            #pragma unroll
            for (int i = 0; i < 32; ++i) a[i] = fmaf(v, wr[i], a[i]);
        }
    }
    #pragma unroll
    for (int i = 0; i < 32; ++i) Abuf[(ob + i) * 64 + lane] = fmaxf(a[i], 0.f);
    __syncthreads();

    // ---- P2: enc h2 = relu(h1@w2 + b2) -> Bbuf
    #pragma unroll
    for (int i = 0; i < 32; ++i) a[i] = b2[ob + i];
    for (int k = 0; k < HID; ++k) {
        float v = Abuf[k * 64 + lane];
        const float* wr = w2 + k * HID + ob;
        #pragma unroll
        for (int i = 0; i < 32; ++i) a[i] = fmaf(v, wr[i], a[i]);
    }
    #pragma unroll
    for (int i = 0; i < 32; ++i) Bbuf[(ob + i) * 64 + lane] = fmaxf(a[i], 0.f);
    __syncthreads();

    // ---- P3a: P = h2@WC + bfc -> Abuf   (P[c][s])
    #pragma unroll
    for (int i = 0; i < 32; ++i) a[i] = bfc[ob + i];
    for (int k = 0; k < HID; ++k) {
        float v = Bbuf[k * 64 + lane];
        const float* wr = WC + k * NC + ob;
        #pragma unroll
        for (int i = 0; i < 32; ++i) a[i] = fmaf(v, wr[i], a[i]);
    }
    #pragma unroll
    for (int i = 0; i < 32; ++i) Abuf[(ob + i) * 64 + lane] = a[i];

    // ---- P3b: ||rep||^2 partial = sum_o (t_o + 2 u_o) * h2_o,  t = Gm@h2
    {
        float tq[32];
        #pragma unroll
        for (int i = 0; i < 32; ++i) tq[i] = 0.f;
        for (int k = 0; k < HID; ++k) {
            float v = Bbuf[k * 64 + lane];
            const float* wr = Gm + k * NC + ob;
            #pragma unroll
            for (int i = 0; i < 32; ++i) tq[i] = fmaf(v, wr[i], tq[i]);
        }
        float part = 0.f;
        #pragma unroll
        for (int i = 0; i < 32; ++i)
            part = fmaf(tq[i] + 2.f * uu[ob + i], Bbuf[(ob + i) * 64 + lane], part);
        qfb[wv * 64 + lane] = part;
    }
    __syncthreads();

    // ---- P4: residual-VQ scoring (wave 0, lane = sample)
    if (wv == 0) {
        float R = qfb[lane] + qfb[64 + lane] + qfb[128 + lane] + qfb[192 + lane] + bb;
        float vqp = 0.f;
        int c0, c1, c2, c3;
        float best, rcb, rc, sc;
        int kb;

        // group 0: score = ||c||^2 - 2 rep·c
        best = 1e30f; kb = 0; rcb = 0.f;
        #pragma unroll
        for (int cc = 0; cc < 32; ++cc) {
            rc = Abuf[cc * 64 + lane];
            sc = cbn2[cc] - 2.f * rc;
            if (sc < best) { best = sc; kb = cc; rcb = rc; }
        }
        c0 = kb;
        { float q2 = cbn2[kb]; float dlt = q2 - 2.f * rcb; vqp += R + dlt; R += dlt; }

        // group 1
        best = 1e30f; kb = 0; rcb = 0.f;
        {
            const float* gr01 = Gram + ((0 * 4 + 1) * 32 + c0) * 32;
            #pragma unroll
            for (int cc = 0; cc < 32; ++cc) {
                rc = Abuf[(32 + cc) * 64 + lane] - gr01[cc];
                sc = cbn2[32 + cc] - 2.f * rc;
                if (sc < best) { best = sc; kb = cc; rcb = rc; }
            }
        }
        c1 = kb;
        { float q2 = cbn2[32 + kb]; float dlt = q2 - 2.f * rcb; vqp += R + dlt; R += dlt; }

        // group 2
        best = 1e30f; kb = 0; rcb = 0.f;
        {
            const float* gr02 = Gram + ((0 * 4 + 2) * 32 + c0) * 32;
            const float* gr12 = Gram + ((1 * 4 + 2) * 32 + c1) * 32;
            #pragma unroll
            for (int cc = 0; cc < 32; ++cc) {
                rc = Abuf[(64 + cc) * 64 + lane] - gr02[cc] - gr12[cc];
                sc = cbn2[64 + cc] - 2.f * rc;
                if (sc < best) { best = sc; kb = cc; rcb = rc; }
            }
        }
        c2 = kb;
        { float q2 = cbn2[64 + kb]; float dlt = q2 - 2.f * rcb; vqp += R + dlt; R += dlt; }

        // group 3
        best = 1e30f; kb = 0; rcb = 0.f;
        {
            const float* gr03 = Gram + ((0 * 4 + 3) * 32 + c0) * 32;
            const float* gr13 = Gram + ((1 * 4 + 3) * 32 + c1) * 32;
            const float* gr23 = Gram + ((2 * 4 + 3) * 32 + c2) * 32;
            #pragma unroll
            for (int cc = 0; cc < 32; ++cc) {
                rc = Abuf[(96 + cc) * 64 + lane] - gr03[cc] - gr13[cc] - gr23[cc];
                sc = cbn2[96 + cc] - 2.f * rc;
                if (sc < best) { best = sc; kb = cc; rcb = rc; }
            }
        }
        c3 = kb;
        { float q2 = cbn2[96 + kb]; float dlt = q2 - 2.f * rcb; vqp += dlt + R; }

        cbuf[0 * 64 + lane] = c0; cbuf[1 * 64 + lane] = c1;
        cbuf[2 * 64 + lane] = c2; cbuf[3 * 64 + lane] = c3;
        float* op = out + 1 + s_glob * 4;
        op[0] = (float)c0; op[1] = (float)c1; op[2] = (float)c2; op[3] = (float)c3;

        float vs = vqp;
        #pragma unroll
        for (int off = 32; off > 0; off >>= 1) vs += __shfl_down(vs, off);
        if (lane == 0) atomicAdd(acc + 0, (double)vs);
    }
    __syncthreads();

    // ---- P5: dec h1 = relu(b1d + sum_g Mdec[g*32+k_g]) -> Bbuf
    {
        int cc0 = cbuf[lane], cc1 = cbuf[64 + lane], cc2 = cbuf[128 + lane], cc3 = cbuf[192 + lane];
        const float* m0 = Mdec + (0 * 32 + cc0) * HID + ob;
        const float* m1 = Mdec + (1 * 32 + cc1) * HID + ob;
        const float* m2 = Mdec + (2 * 32 + cc2) * HID + ob;
        const float* m3 = Mdec + (3 * 32 + cc3) * HID + ob;
        #pragma unroll
        for (int i = 0; i < 32; ++i) {
            float v = b1d[ob + i] + m0[i] + m1[i] + m2[i] + m3[i];
            Bbuf[(ob + i) * 64 + lane] = fmaxf(v, 0.f);
        }
    }
    __syncthreads();

    // ---- P6: dec h2 = relu(h@w2d + b2d) -> Abuf
    #pragma unroll
    for (int i = 0; i < 32; ++i) a[i] = b2d[ob + i];
    for (int k = 0; k < HID; ++k) {
        float v = Bbuf[k * 64 + lane];
        const float* wr = w2d + k * HID + ob;
        #pragma unroll
        for (int i = 0; i < 32; ++i) a[i] = fmaf(v, wr[i], a[i]);
    }
    #pragma unroll
    for (int i = 0; i < 32; ++i) Abuf[(ob + i) * 64 + lane] = fmaxf(a[i], 0.f);
    __syncthreads();

    // ---- P7: dec out (90) + losses; wave wv covers o in [wv*23, wv*23+23) clamped
    float labs = 0.f, lsq = 0.f;
    {
        const int o0 = wv * 23;
        float a7[23];
        #pragma unroll
        for (int i = 0; i < 23; ++i) { int oi = min(o0 + i, SIN - 1); a7[i] = bfd[oi]; }
        for (int k = 0; k < HID; ++k) {
            float v = Abuf[k * 64 + lane];
            const float* wr = wfd + k * SIN;
            #pragma unroll
            for (int i = 0; i < 23; ++i) { int oi = min(o0 + i, SIN - 1); a7[i] = fmaf(v, wr[oi], a7[i]); }
        }
        const float* xr = x + s_glob * SIN;
        #pragma unroll
        for (int i = 0; i < 23; ++i) {
            int o = o0 + i;
            if (o < SIN) {
                float e = a7[i] - xr[o];
                labs += fabsf(e);
                lsq  = fmaf(e, e, lsq);
            }
        }
    }
    #pragma unroll
    for (int off = 32; off > 0; off >>= 1) {
        labs += __shfl_down(labs, off);
        lsq  += __shfl_down(lsq, off);
    }
    if (lane == 0) { red[wv] = labs; red[4 + wv] = lsq; }
    __syncthreads();
    if (t == 0) {
        float A1 = red[0] + red[1] + red[2] + red[3];
        float S1 = red[4] + red[5] + red[6] + red[7];
        atomicAdd(acc + 1, (double)A1);
        atomicAdd(acc + 2, (double)S1);
    }
}

__global__ void k_fin(const double* __restrict__ acc, float* __restrict__ out, int Bn) {
    if (threadIdx.x == 0 && blockIdx.x == 0) {
        double vq = acc[0] / ((double)Bn * (double)DLAT);
        double el = acc[1] / ((double)Bn * (double)SIN);
        double rc = acc[2] / ((double)Bn * (double)SIN);
        long co = 1 + (long)Bn * 4;
        out[0]      = (float)(el + 5.0 * vq);   // loss = encoder_loss*1 + vq_loss*5
        out[co]     = (float)vq;
        out[co + 1] = (float)rc;
        out[co + 2] = (float)el;
    }
}

extern "C" void kernel_launch(void* const* d_in, const int* in_sizes, int n_in,
                              void* d_out, int out_size, void* d_ws, size_t ws_size,
                              hipStream_t stream) {
    (void)n_in; (void)out_size; (void)ws_size;
    const float* x   = (const float*)d_in[0];
    const float* w1  = (const float*)d_in[1];
    const float* b1  = (const float*)d_in[2];
    const float* w2  = (const float*)d_in[3];
    const float* b2  = (const float*)d_in[4];
    const float* wf  = (const float*)d_in[5];
    const float* bf  = (const float*)d_in[6];
    const float* w1d = (const float*)d_in[7];
    const float* b1d = (const float*)d_in[8];
    const float* w2d = (const float*)d_in[9];
    const float* b2d = (const float*)d_in[10];
    const float* wfd = (const float*)d_in[11];
    const float* bfd = (const float*)d_in[12];
    const float* cb  = (const float*)d_in[13];

    float* out  = (float*)d_out;
    double* acc = (double*)d_ws;
    float* pre  = (float*)d_ws + 16;   // 64B offset, keeps doubles aligned

    int Bn = in_sizes[0] / SIN;

    hipLaunchKernelGGL(k_zero, dim3(1), dim3(64), 0, stream, acc);
    hipLaunchKernelGGL(k_pre, dim3((PRE_N + 255) / 256), dim3(256), 0, stream,
                       wf, bf, w1d, cb, pre);
    hipLaunchKernelGGL(k_main, dim3(Bn / 64), dim3(256), 0, stream,
                       x, w1, b1, w2, b2, b1d, w2d, b2d, wfd, bfd, pre, out, acc, Bn);
    hipLaunchKernelGGL(k_fin, dim3(1), dim3(64), 0, stream, acc, out, Bn);
}

// Round 2
// 542.870 us; speedup vs baseline: 1.2853x; 1.2853x over previous
//
#include <hip/hip_runtime.h>

// VQ-VAE fused forward, f32 throughout.
// Algebraic restructuring: all 512-dim contractions folded into precomputed
// 128x128 (or smaller) matrices:
//   WC[k][c]  = enc_wf[k,:]·cb[c,:]          (P = rep·cb^T = h2@WC + bfc)
//   Gm[o][k]  = enc_wf[o,:]·enc_wf[k,:]      (||rep||^2 = h2^T Gm h2 + 2 u·h2 + bb)
//   Mdec[r][j]= cb[r,:]·dec_w1[:,j]          (dec h1 preact = b1d + sum_g Mdec[g*32+k_g])
//   Gram[ga,gb,ka,kb] = cb_ga[ka,:]·cb_gb[kb,:]  (residual dots across groups)
// R2: 512-thread blocks (8 waves x 16-dim chunks, wave-uniform via
// readfirstlane -> scalar weight loads), fused P3a+P3b, LDS-staged x tile
// (stride 91 = conflict-free), float4 k_pre. Occupancy 2 blk/CU * 8 waves
// = 16 waves/CU (50% cap) vs 8 before.

#define SIN  90
#define XST  91     // x stage stride (odd vs 32 banks -> conflict-free)
#define HID  128
#define DLAT 512
#define NC   128   // total codes (4*32)
#define GQ   4

// ws float layout, after 8 doubles (64 bytes) of accumulators:
//   [0,16384)      WC
//   [16384,32768)  Gm
//   [32768,49152)  Mdec  (row = g*32+k, col j)
//   [49152,65536)  Gram  idx = ((ga*4+gb)*32+ka)*32+kb
//   [65536,65664)  cbn2[128]
//   [65664,65792)  u[128]      (wf·bf)
//   [65792,65920)  bfc[128]    (bf·cb_c)
//   [65920]        bb = ||bf||^2
#define PRE_N 65921

__global__ void k_zero(double* __restrict__ acc) {
    if (threadIdx.x < 4) acc[threadIdx.x] = 0.0;
}

__device__ __forceinline__ float dot512(const float* __restrict__ a,
                                        const float* __restrict__ b) {
    const float4* a4 = (const float4*)a;
    const float4* b4 = (const float4*)b;
    float s = 0.f;
    for (int d = 0; d < DLAT / 4; ++d) {
        float4 av = a4[d], bv = b4[d];
        s = fmaf(av.x, bv.x, s);
        s = fmaf(av.y, bv.y, s);
        s = fmaf(av.z, bv.z, s);
        s = fmaf(av.w, bv.w, s);
    }
    return s;
}

__global__ void k_pre(const float* __restrict__ wf, const float* __restrict__ bf,
                      const float* __restrict__ w1d, const float* __restrict__ cb,
                      float* __restrict__ P) {
    int idx = blockIdx.x * 256 + threadIdx.x;
    if (idx >= PRE_N) return;
    float s = 0.f;
    if (idx < 16384) {
        int k = idx >> 7, c = idx & 127;
        s = dot512(wf + k * DLAT, cb + c * DLAT);
    } else if (idx < 32768) {
        int r = idx - 16384; int o = r >> 7, k = r & 127;
        s = dot512(wf + o * DLAT, wf + k * DLAT);
    } else if (idx < 49152) {
        int r = idx - 32768; int row = r >> 7, j = r & 127;
        const float* a = cb + row * DLAT;
        for (int d = 0; d < DLAT; ++d) s = fmaf(a[d], w1d[d * HID + j], s);
    } else if (idx < 65536) {
        int r = idx - 49152;
        int kb = r & 31, ka = (r >> 5) & 31, gb = (r >> 10) & 3, ga = (r >> 12) & 3;
        s = dot512(cb + (ga * 32 + ka) * DLAT, cb + (gb * 32 + kb) * DLAT);
    } else if (idx < 65664) {
        int c = idx - 65536;
        s = dot512(cb + c * DLAT, cb + c * DLAT);
    } else if (idx < 65792) {
        int k = idx - 65664;
        s = dot512(wf + k * DLAT, bf);
    } else if (idx < 65920) {
        int c = idx - 65792;
        s = dot512(bf, cb + c * DLAT);
    } else {
        s = dot512(bf, bf);
    }
    P[idx] = s;
}

#define CH 16   // out dims per wave

__global__ __launch_bounds__(512, 4) void k_main(
    const float* __restrict__ x,
    const float* __restrict__ w1, const float* __restrict__ b1,
    const float* __restrict__ w2, const float* __restrict__ b2,
    const float* __restrict__ b1d,
    const float* __restrict__ w2d, const float* __restrict__ b2d,
    const float* __restrict__ wfd, const float* __restrict__ bfd,
    const float* __restrict__ pre,
    float* __restrict__ out, double* __restrict__ acc, int Bn)
{
    __shared__ float Abuf[HID * 64];
    __shared__ float Bbuf[HID * 64];
    __shared__ float qfb[8 * 64];
    __shared__ int   cbuf[4 * 64];
    __shared__ float red[16];

    const int t = threadIdx.x;
    const int lane = t & 63;
    const int wv = t >> 6;                                    // 0..7
    const int ob = __builtin_amdgcn_readfirstlane(wv) * CH;   // wave-uniform chunk base
    const long s_glob = (long)blockIdx.x * 64 + lane;

    const float* WC   = pre;
    const float* Gm   = pre + 16384;
    const float* Mdec = pre + 32768;
    const float* Gram = pre + 49152;
    const float* cbn2 = pre + 65536;
    const float* uu   = pre + 65664;
    const float* bfc  = pre + 65792;
    const float  bb   = pre[65920];

    float a[CH];

    // ---- P0: stage x tile into Bbuf, [s][k] at stride 91 (coalesced global)
    {
        const float* xb = x + (long)blockIdx.x * 64 * SIN;
        for (int i = t; i < 64 * SIN; i += 512) {
            int s = i / SIN;
            int k = i - s * SIN;
            Bbuf[s * XST + k] = xb[i];
        }
    }
    __syncthreads();

    // ---- P1: enc h1 = relu(x@w1 + b1) -> Abuf[dim][64]
    #pragma unroll
    for (int i = 0; i < CH; ++i) a[i] = b1[ob + i];
    for (int k = 0; k < SIN; ++k) {
        float v = Bbuf[lane * XST + k];
        const float* wr = w1 + k * HID + ob;
        #pragma unroll
        for (int i = 0; i < CH; ++i) a[i] = fmaf(v, wr[i], a[i]);
    }
    #pragma unroll
    for (int i = 0; i < CH; ++i) Abuf[(ob + i) * 64 + lane] = fmaxf(a[i], 0.f);
    __syncthreads();

    // ---- P2: enc h2 = relu(h1@w2 + b2) -> Bbuf (x tile dead)
    #pragma unroll
    for (int i = 0; i < CH; ++i) a[i] = b2[ob + i];
    for (int k = 0; k < HID; ++k) {
        float v = Abuf[k * 64 + lane];
        const float* wr = w2 + k * HID + ob;
        #pragma unroll
        for (int i = 0; i < CH; ++i) a[i] = fmaf(v, wr[i], a[i]);
    }
    #pragma unroll
    for (int i = 0; i < CH; ++i) Bbuf[(ob + i) * 64 + lane] = fmaxf(a[i], 0.f);
    __syncthreads();

    // ---- P3 (fused): P = h2@WC + bfc -> Abuf; t = Gm@h2 for ||rep||^2 partial
    {
        float tq[CH];
        #pragma unroll
        for (int i = 0; i < CH; ++i) { a[i] = bfc[ob + i]; tq[i] = 0.f; }
        for (int k = 0; k < HID; ++k) {
            float v = Bbuf[k * 64 + lane];
            const float* wr = WC + k * NC + ob;
            const float* gr = Gm + k * NC + ob;
            #pragma unroll
            for (int i = 0; i < CH; ++i) {
                a[i]  = fmaf(v, wr[i], a[i]);
                tq[i] = fmaf(v, gr[i], tq[i]);
            }
        }
        float part = 0.f;
        #pragma unroll
        for (int i = 0; i < CH; ++i)
            part = fmaf(tq[i] + 2.f * uu[ob + i], Bbuf[(ob + i) * 64 + lane], part);
        qfb[wv * 64 + lane] = part;
        #pragma unroll
        for (int i = 0; i < CH; ++i) Abuf[(ob + i) * 64 + lane] = a[i];
    }
    __syncthreads();

    // ---- P4: residual-VQ scoring (wave 0, lane = sample)
    if (wv == 0) {
        float R = bb;
        #pragma unroll
        for (int w = 0; w < 8; ++w) R += qfb[w * 64 + lane];
        float vqp = 0.f;
        int c0, c1, c2, c3;
        float best, rcb, rc, sc;
        int kb;

        // group 0: score = ||c||^2 - 2 rep·c
        best = 1e30f; kb = 0; rcb = 0.f;
        #pragma unroll
        for (int cc = 0; cc < 32; ++cc) {
            rc = Abuf[cc * 64 + lane];
            sc = cbn2[cc] - 2.f * rc;
            if (sc < best) { best = sc; kb = cc; rcb = rc; }
        }
        c0 = kb;
        { float q2 = cbn2[kb]; float dlt = q2 - 2.f * rcb; vqp += R + dlt; R += dlt; }

        // group 1
        best = 1e30f; kb = 0; rcb = 0.f;
        {
            const float* gr01 = Gram + ((0 * 4 + 1) * 32 + c0) * 32;
            #pragma unroll
            for (int cc = 0; cc < 32; ++cc) {
                rc = Abuf[(32 + cc) * 64 + lane] - gr01[cc];
                sc = cbn2[32 + cc] - 2.f * rc;
                if (sc < best) { best = sc; kb = cc; rcb = rc; }
            }
        }
        c1 = kb;
        { float q2 = cbn2[32 + kb]; float dlt = q2 - 2.f * rcb; vqp += R + dlt; R += dlt; }

        // group 2
        best = 1e30f; kb = 0; rcb = 0.f;
        {
            const float* gr02 = Gram + ((0 * 4 + 2) * 32 + c0) * 32;
            const float* gr12 = Gram + ((1 * 4 + 2) * 32 + c1) * 32;
            #pragma unroll
            for (int cc = 0; cc < 32; ++cc) {
                rc = Abuf[(64 + cc) * 64 + lane] - gr02[cc] - gr12[cc];
                sc = cbn2[64 + cc] - 2.f * rc;
                if (sc < best) { best = sc; kb = cc; rcb = rc; }
            }
        }
        c2 = kb;
        { float q2 = cbn2[64 + kb]; float dlt = q2 - 2.f * rcb; vqp += R + dlt; R += dlt; }

        // group 3
        best = 1e30f; kb = 0; rcb = 0.f;
        {
            const float* gr03 = Gram + ((0 * 4 + 3) * 32 + c0) * 32;
            const float* gr13 = Gram + ((1 * 4 + 3) * 32 + c1) * 32;
            const float* gr23 = Gram + ((2 * 4 + 3) * 32 + c2) * 32;
            #pragma unroll
            for (int cc = 0; cc < 32; ++cc) {
                rc = Abuf[(96 + cc) * 64 + lane] - gr03[cc] - gr13[cc] - gr23[cc];
                sc = cbn2[96 + cc] - 2.f * rc;
                if (sc < best) { best = sc; kb = cc; rcb = rc; }
            }
        }
        c3 = kb;
        { float q2 = cbn2[96 + kb]; float dlt = q2 - 2.f * rcb; vqp += dlt + R; }

        cbuf[0 * 64 + lane] = c0; cbuf[1 * 64 + lane] = c1;
        cbuf[2 * 64 + lane] = c2; cbuf[3 * 64 + lane] = c3;
        float* op = out + 1 + s_glob * 4;
        op[0] = (float)c0; op[1] = (float)c1; op[2] = (float)c2; op[3] = (float)c3;

        float vs = vqp;
        #pragma unroll
        for (int off = 32; off > 0; off >>= 1) vs += __shfl_down(vs, off);
        if (lane == 0) atomicAdd(acc + 0, (double)vs);
    }
    __syncthreads();

    // ---- P5: dec h1 = relu(b1d + sum_g Mdec[g*32+k_g]) -> Bbuf (h2 dead)
    {
        int cc0 = cbuf[lane], cc1 = cbuf[64 + lane], cc2 = cbuf[128 + lane], cc3 = cbuf[192 + lane];
        const float* m0 = Mdec + (0 * 32 + cc0) * HID + ob;
        const float* m1 = Mdec + (1 * 32 + cc1) * HID + ob;
        const float* m2 = Mdec + (2 * 32 + cc2) * HID + ob;
        const float* m3 = Mdec + (3 * 32 + cc3) * HID + ob;
        #pragma unroll
        for (int i = 0; i < CH; ++i) {
            float v = b1d[ob + i] + m0[i] + m1[i] + m2[i] + m3[i];
            Bbuf[(ob + i) * 64 + lane] = fmaxf(v, 0.f);
        }
    }
    __syncthreads();

    // ---- P6: dec h2 = relu(h@w2d + b2d) -> Abuf (P dead)
    #pragma unroll
    for (int i = 0; i < CH; ++i) a[i] = b2d[ob + i];
    for (int k = 0; k < HID; ++k) {
        float v = Bbuf[k * 64 + lane];
        const float* wr = w2d + k * HID + ob;
        #pragma unroll
        for (int i = 0; i < CH; ++i) a[i] = fmaf(v, wr[i], a[i]);
    }
    #pragma unroll
    for (int i = 0; i < CH; ++i) Abuf[(ob + i) * 64 + lane] = fmaxf(a[i], 0.f);
    __syncthreads();

    // ---- P7: dec out (90) + losses; wave wv covers o in [wv*12, wv*12+12) clamped
    float labs = 0.f, lsq = 0.f;
    {
        const int o0 = wv * 12;
        float a7[12];
        #pragma unroll
        for (int i = 0; i < 12; ++i) { int oi = min(o0 + i, SIN - 1); a7[i] = bfd[oi]; }
        for (int k = 0; k < HID; ++k) {
            float v = Abuf[k * 64 + lane];
            const float* wr = wfd + k * SIN;
            #pragma unroll
            for (int i = 0; i < 12; ++i) { int oi = min(o0 + i, SIN - 1); a7[i] = fmaf(v, wr[oi], a7[i]); }
        }
        const float* xr = x + s_glob * SIN;
        #pragma unroll
        for (int i = 0; i < 12; ++i) {
            int o = o0 + i;
            if (o < SIN) {
                float e = a7[i] - xr[o];
                labs += fabsf(e);
                lsq  = fmaf(e, e, lsq);
            }
        }
    }
    #pragma unroll
    for (int off = 32; off > 0; off >>= 1) {
        labs += __shfl_down(labs, off);
        lsq  += __shfl_down(lsq, off);
    }
    if (lane == 0) { red[wv] = labs; red[8 + wv] = lsq; }
    __syncthreads();
    if (t == 0) {
        float A1 = 0.f, S1 = 0.f;
        #pragma unroll
        for (int w = 0; w < 8; ++w) { A1 += red[w]; S1 += red[8 + w]; }
        atomicAdd(acc + 1, (double)A1);
        atomicAdd(acc + 2, (double)S1);
    }
}

__global__ void k_fin(const double* __restrict__ acc, float* __restrict__ out, int Bn) {
    if (threadIdx.x == 0 && blockIdx.x == 0) {
        double vq = acc[0] / ((double)Bn * (double)DLAT);
        double el = acc[1] / ((double)Bn * (double)SIN);
        double rc = acc[2] / ((double)Bn * (double)SIN);
        long co = 1 + (long)Bn * 4;
        out[0]      = (float)(el + 5.0 * vq);   // loss = encoder_loss*1 + vq_loss*5
        out[co]     = (float)vq;
        out[co + 1] = (float)rc;
        out[co + 2] = (float)el;
    }
}

extern "C" void kernel_launch(void* const* d_in, const int* in_sizes, int n_in,
                              void* d_out, int out_size, void* d_ws, size_t ws_size,
                              hipStream_t stream) {
    (void)n_in; (void)out_size; (void)ws_size;
    const float* x   = (const float*)d_in[0];
    const float* w1  = (const float*)d_in[1];
    const float* b1  = (const float*)d_in[2];
    const float* w2  = (const float*)d_in[3];
    const float* b2  = (const float*)d_in[4];
    const float* wf  = (const float*)d_in[5];
    const float* bf  = (const float*)d_in[6];
    const float* w1d = (const float*)d_in[7];
    const float* b1d = (const float*)d_in[8];
    const float* w2d = (const float*)d_in[9];
    const float* b2d = (const float*)d_in[10];
    const float* wfd = (const float*)d_in[11];
    const float* bfd = (const float*)d_in[12];
    const float* cb  = (const float*)d_in[13];

    float* out  = (float*)d_out;
    double* acc = (double*)d_ws;
    float* pre  = (float*)d_ws + 16;   // 64B offset, keeps doubles aligned

    int Bn = in_sizes[0] / SIN;

    hipLaunchKernelGGL(k_zero, dim3(1), dim3(64), 0, stream, acc);
    hipLaunchKernelGGL(k_pre, dim3((PRE_N + 255) / 256), dim3(256), 0, stream,
                       wf, bf, w1d, cb, pre);
    hipLaunchKernelGGL(k_main, dim3(Bn / 64), dim3(512), 0, stream,
                       x, w1, b1, w2, b2, b1d, w2d, b2d, wfd, bfd, pre, out, acc, Bn);
    hipLaunchKernelGGL(k_fin, dim3(1), dim3(64), 0, stream, acc, out, Bn);
}

// Round 3
// 514.517 us; speedup vs baseline: 1.3561x; 1.0551x over previous
//
#include <hip/hip_runtime.h>

// VQ-VAE fused forward, f32 throughout.
// Algebra: all 512-dim contractions folded into precomputed tables:
//   WC[k][c]  = enc_wf[k,:]·cb[c,:]          (P = rep·cb^T = h2@WC + bfc)
//   Gm[o][k]  = enc_wf[o,:]·enc_wf[k,:]      (||rep||^2 = h2^T Gm h2 + 2 u·h2 + bb)
//   Mdec[r][j]= cb[r,:]·dec_w1[:,j]          (dec h1 preact = b1d + sum_g Mdec[g*32+k_g])
//   Gram[ga,gb,ka,kb] = cb_ga[ka,:]·cb_gb[kb,:]  (residual dots across groups)
// R3: single in-place LDS buffer H[64][132] (36KB -> 4 blk/CU = 32 waves/CU),
// [sample][dim] layout so each thread streams its own row via ds_read_b128
// (stride 132: 16B-aligned, b128 conflict-free). Phases: read-all -> barrier
// -> write-own-slice -> barrier. launch_bounds(512,8) caps VGPR at 64.

#define SIN  90
#define HID  128
#define DLAT 512
#define NC   128
#define HST  132    // H row stride (dwords): %4==0 (b128 align), %32==4 (bank spread)

// ws float layout, after 8 doubles (64 bytes) of accumulators:
//   [0,16384)      WC
//   [16384,32768)  Gm
//   [32768,49152)  Mdec  (row = g*32+k, col j)
//   [49152,65536)  Gram  idx = ((ga*4+gb)*32+ka)*32+kb
//   [65536,65664)  cbn2[128]
//   [65664,65792)  u[128]      (wf·bf)
//   [65792,65920)  bfc[128]    (bf·cb_c)
//   [65920]        bb = ||bf||^2
#define PRE_N 65921

__device__ __forceinline__ float dot512(const float* __restrict__ a,
                                        const float* __restrict__ b) {
    const float4* a4 = (const float4*)a;
    const float4* b4 = (const float4*)b;
    float s = 0.f;
    for (int d = 0; d < DLAT / 4; ++d) {
        float4 av = a4[d], bv = b4[d];
        s = fmaf(av.x, bv.x, s);
        s = fmaf(av.y, bv.y, s);
        s = fmaf(av.z, bv.z, s);
        s = fmaf(av.w, bv.w, s);
    }
    return s;
}

__global__ void k_pre(const float* __restrict__ wf, const float* __restrict__ bf,
                      const float* __restrict__ w1d, const float* __restrict__ cb,
                      float* __restrict__ P, double* __restrict__ acc) {
    int idx = blockIdx.x * 256 + threadIdx.x;
    if (idx < 4) acc[idx] = 0.0;          // folded k_zero
    if (idx >= PRE_N) return;
    float s = 0.f;
    if (idx < 16384) {
        int k = idx >> 7, c = idx & 127;
        s = dot512(wf + k * DLAT, cb + c * DLAT);
    } else if (idx < 32768) {
        int r = idx - 16384; int o = r >> 7, k = r & 127;
        s = dot512(wf + o * DLAT, wf + k * DLAT);
    } else if (idx < 49152) {
        int r = idx - 32768; int row = r >> 7, j = r & 127;
        const float* a = cb + row * DLAT;
        for (int d = 0; d < DLAT; ++d) s = fmaf(a[d], w1d[d * HID + j], s);
    } else if (idx < 65536) {
        int r = idx - 49152;
        int kb = r & 31, ka = (r >> 5) & 31, gb = (r >> 10) & 3, ga = (r >> 12) & 3;
        s = dot512(cb + (ga * 32 + ka) * DLAT, cb + (gb * 32 + kb) * DLAT);
    } else if (idx < 65664) {
        int c = idx - 65536;
        s = dot512(cb + c * DLAT, cb + c * DLAT);
    } else if (idx < 65792) {
        int k = idx - 65664;
        s = dot512(wf + k * DLAT, bf);
    } else if (idx < 65920) {
        int c = idx - 65792;
        s = dot512(bf, cb + c * DLAT);
    } else {
        s = dot512(bf, bf);
    }
    P[idx] = s;
}

#define CH 16   // out dims per wave (8 waves x 16 = 128)

__global__ __launch_bounds__(512, 8) void k_main(
    const float* __restrict__ x,
    const float* __restrict__ w1, const float* __restrict__ b1,
    const float* __restrict__ w2, const float* __restrict__ b2,
    const float* __restrict__ b1d,
    const float* __restrict__ w2d, const float* __restrict__ b2d,
    const float* __restrict__ wfd, const float* __restrict__ bfd,
    const float* __restrict__ pre,
    float* __restrict__ out, double* __restrict__ acc, int Bn)
{
    __shared__ __align__(16) float H[64 * HST];
    __shared__ float qfb[8 * 64];
    __shared__ int   cbuf[4 * 64];
    __shared__ float red[16];

    const int t = threadIdx.x;
    const int lane = t & 63;
    const int wv = t >> 6;                                    // 0..7
    const int ob = __builtin_amdgcn_readfirstlane(wv) * CH;   // wave-uniform chunk base
    const long s_glob = (long)blockIdx.x * 64 + lane;

    const float* WC   = pre;
    const float* Gm   = pre + 16384;
    const float* Mdec = pre + 32768;
    const float* Gram = pre + 49152;
    const float* cbn2 = pre + 65536;
    const float* uu   = pre + 65664;
    const float* bfc  = pre + 65792;
    const float  bb   = pre[65920];

    const float4* hr = (const float4*)(H + lane * HST);   // own row, b128 stream
    float4*       hw = (float4*)(H + lane * HST + ob);    // own row, own chunk

    float a[CH];

    // ---- P0: stage x tile -> H[s][0..89] (coalesced global reads)
    {
        const float* xb = x + (long)blockIdx.x * 64 * SIN;
        for (int i = t; i < 64 * SIN; i += 512) {
            int s = i / SIN;
            int k = i - s * SIN;
            H[s * HST + k] = xb[i];
        }
    }
    __syncthreads();

    // ---- P1: enc h1 = relu(x@w1 + b1); read own row (x), write own chunk
    #pragma unroll
    for (int i = 0; i < CH; ++i) a[i] = b1[ob + i];
    #pragma unroll 4
    for (int kb = 0; kb < 22; ++kb) {
        float4 v4 = hr[kb];
        #pragma unroll
        for (int j = 0; j < 4; ++j) {
            float v = ((const float*)&v4)[j];
            const float* wr = w1 + (kb * 4 + j) * HID + ob;
            #pragma unroll
            for (int i = 0; i < CH; ++i) a[i] = fmaf(v, wr[i], a[i]);
        }
    }
    #pragma unroll
    for (int k = 88; k < SIN; ++k) {
        float v = H[lane * HST + k];
        const float* wr = w1 + k * HID + ob;
        #pragma unroll
        for (int i = 0; i < CH; ++i) a[i] = fmaf(v, wr[i], a[i]);
    }
    __syncthreads();                      // all x reads done
    #pragma unroll
    for (int i4 = 0; i4 < CH / 4; ++i4) {
        float4 w4;
        #pragma unroll
        for (int j = 0; j < 4; ++j) ((float*)&w4)[j] = fmaxf(a[i4 * 4 + j], 0.f);
        hw[i4] = w4;
    }
    __syncthreads();

    // ---- P2: enc h2 = relu(h1@w2 + b2)
    #pragma unroll
    for (int i = 0; i < CH; ++i) a[i] = b2[ob + i];
    #pragma unroll 4
    for (int kb = 0; kb < 32; ++kb) {
        float4 v4 = hr[kb];
        #pragma unroll
        for (int j = 0; j < 4; ++j) {
            float v = ((const float*)&v4)[j];
            const float* wr = w2 + (kb * 4 + j) * HID + ob;
            #pragma unroll
            for (int i = 0; i < CH; ++i) a[i] = fmaf(v, wr[i], a[i]);
        }
    }
    __syncthreads();
    #pragma unroll
    for (int i4 = 0; i4 < CH / 4; ++i4) {
        float4 w4;
        #pragma unroll
        for (int j = 0; j < 4; ++j) ((float*)&w4)[j] = fmaxf(a[i4 * 4 + j], 0.f);
        hw[i4] = w4;
    }
    __syncthreads();

    // ---- P3 (fused): P = h2@WC + bfc; tq = Gm@h2 for ||rep||^2 partial
    {
        float tq[CH];
        #pragma unroll
        for (int i = 0; i < CH; ++i) { a[i] = bfc[ob + i]; tq[i] = 0.f; }
        #pragma unroll 4
        for (int kb = 0; kb < 32; ++kb) {
            float4 v4 = hr[kb];
            #pragma unroll
            for (int j = 0; j < 4; ++j) {
                float v = ((const float*)&v4)[j];
                const float* wr = WC + (kb * 4 + j) * NC + ob;
                const float* gr = Gm + (kb * 4 + j) * NC + ob;
                #pragma unroll
                for (int i = 0; i < CH; ++i) {
                    a[i]  = fmaf(v, wr[i], a[i]);
                    tq[i] = fmaf(v, gr[i], tq[i]);
                }
            }
        }
        // own h2 chunk for the quadratic-form partial
        float part = 0.f;
        #pragma unroll
        for (int i4 = 0; i4 < CH / 4; ++i4) {
            float4 h4 = hr[ob / 4 + i4];
            #pragma unroll
            for (int j = 0; j < 4; ++j) {
                int i = i4 * 4 + j;
                part = fmaf(tq[i] + 2.f * uu[ob + i], ((const float*)&h4)[j], part);
            }
        }
        qfb[wv * 64 + lane] = part;
        __syncthreads();                  // all h2 reads done
        #pragma unroll
        for (int i4 = 0; i4 < CH / 4; ++i4) {
            float4 w4;
            #pragma unroll
            for (int j = 0; j < 4; ++j) ((float*)&w4)[j] = a[i4 * 4 + j];
            hw[i4] = w4;
        }
    }
    __syncthreads();

    // ---- P4: residual-VQ scoring (wave 0, lane = sample; row = P[c])
    if (wv == 0) {
        float R = bb;
        #pragma unroll
        for (int w = 0; w < 8; ++w) R += qfb[w * 64 + lane];
        float vqp = 0.f;
        int c0, c1, c2, c3;
        float best, rcb, rc, sc;
        int kb;

        // group 0: score = ||c||^2 - 2 rep·c
        best = 1e30f; kb = 0; rcb = 0.f;
        #pragma unroll
        for (int cq = 0; cq < 8; ++cq) {
            float4 p4 = hr[cq];
            #pragma unroll
            for (int j = 0; j < 4; ++j) {
                int cc = cq * 4 + j;
                rc = ((const float*)&p4)[j];
                sc = cbn2[cc] - 2.f * rc;
                if (sc < best) { best = sc; kb = cc; rcb = rc; }
            }
        }
        c0 = kb;
        { float dlt = cbn2[kb] - 2.f * rcb; vqp += R + dlt; R += dlt; }

        // group 1
        best = 1e30f; kb = 0; rcb = 0.f;
        {
            const float4* gr01 = (const float4*)(Gram + ((0 * 4 + 1) * 32 + c0) * 32);
            #pragma unroll
            for (int cq = 0; cq < 8; ++cq) {
                float4 p4 = hr[8 + cq];
                float4 g4 = gr01[cq];
                #pragma unroll
                for (int j = 0; j < 4; ++j) {
                    int cc = cq * 4 + j;
                    rc = ((const float*)&p4)[j] - ((const float*)&g4)[j];
                    sc = cbn2[32 + cc] - 2.f * rc;
                    if (sc < best) { best = sc; kb = cc; rcb = rc; }
                }
            }
        }
        c1 = kb;
        { float dlt = cbn2[32 + kb] - 2.f * rcb; vqp += R + dlt; R += dlt; }

        // group 2
        best = 1e30f; kb = 0; rcb = 0.f;
        {
            const float4* gr02 = (const float4*)(Gram + ((0 * 4 + 2) * 32 + c0) * 32);
            const float4* gr12 = (const float4*)(Gram + ((1 * 4 + 2) * 32 + c1) * 32);
            #pragma unroll
            for (int cq = 0; cq < 8; ++cq) {
                float4 p4 = hr[16 + cq];
                float4 g04 = gr02[cq];
                float4 g14 = gr12[cq];
                #pragma unroll
                for (int j = 0; j < 4; ++j) {
                    int cc = cq * 4 + j;
                    rc = ((const float*)&p4)[j] - ((const float*)&g04)[j] - ((const float*)&g14)[j];
                    sc = cbn2[64 + cc] - 2.f * rc;
                    if (sc < best) { best = sc; kb = cc; rcb = rc; }
                }
            }
        }
        c2 = kb;
        { float dlt = cbn2[64 + kb] - 2.f * rcb; vqp += R + dlt; R += dlt; }

        // group 3
        best = 1e30f; kb = 0; rcb = 0.f;
        {
            const float4* gr03 = (const float4*)(Gram + ((0 * 4 + 3) * 32 + c0) * 32);
            const float4* gr13 = (const float4*)(Gram + ((1 * 4 + 3) * 32 + c1) * 32);
            const float4* gr23 = (const float4*)(Gram + ((2 * 4 + 3) * 32 + c2) * 32);
            #pragma unroll
            for (int cq = 0; cq < 8; ++cq) {
                float4 p4 = hr[24 + cq];
                float4 g04 = gr03[cq];
                float4 g14 = gr13[cq];
                float4 g24 = gr23[cq];
                #pragma unroll
                for (int j = 0; j < 4; ++j) {
                    int cc = cq * 4 + j;
                    rc = ((const float*)&p4)[j] - ((const float*)&g04)[j]
                       - ((const float*)&g14)[j] - ((const float*)&g24)[j];
                    sc = cbn2[96 + cc] - 2.f * rc;
                    if (sc < best) { best = sc; kb = cc; rcb = rc; }
                }
            }
        }
        c3 = kb;
        { float dlt = cbn2[96 + kb] - 2.f * rcb; vqp += dlt + R; }

        cbuf[0 * 64 + lane] = c0; cbuf[1 * 64 + lane] = c1;
        cbuf[2 * 64 + lane] = c2; cbuf[3 * 64 + lane] = c3;
        float* op = out + 1 + s_glob * 4;
        op[0] = (float)c0; op[1] = (float)c1; op[2] = (float)c2; op[3] = (float)c3;

        float vs = vqp;
        #pragma unroll
        for (int off = 32; off > 0; off >>= 1) vs += __shfl_down(vs, off);
        if (lane == 0) atomicAdd(acc + 0, (double)vs);
    }
    __syncthreads();                      // wave0 P reads done

    // ---- P5: dec h1 = relu(b1d + sum_g Mdec[g*32+k_g]); write own chunk
    {
        int cc0 = cbuf[lane], cc1 = cbuf[64 + lane], cc2 = cbuf[128 + lane], cc3 = cbuf[192 + lane];
        const float4* m0 = (const float4*)(Mdec + (0 * 32 + cc0) * HID + ob);
        const float4* m1 = (const float4*)(Mdec + (1 * 32 + cc1) * HID + ob);
        const float4* m2 = (const float4*)(Mdec + (2 * 32 + cc2) * HID + ob);
        const float4* m3 = (const float4*)(Mdec + (3 * 32 + cc3) * HID + ob);
        const float4* bd = (const float4*)(b1d + ob);
        #pragma unroll
        for (int i4 = 0; i4 < CH / 4; ++i4) {
            float4 v0 = m0[i4], v1 = m1[i4], v2 = m2[i4], v3 = m3[i4], vb = bd[i4];
            float4 w4;
            #pragma unroll
            for (int j = 0; j < 4; ++j) {
                float v = ((const float*)&vb)[j] + ((const float*)&v0)[j] + ((const float*)&v1)[j]
                        + ((const float*)&v2)[j] + ((const float*)&v3)[j];
                ((float*)&w4)[j] = fmaxf(v, 0.f);
            }
            hw[i4] = w4;
        }
    }
    __syncthreads();

    // ---- P6: dec h2 = relu(h@w2d + b2d)
    #pragma unroll
    for (int i = 0; i < CH; ++i) a[i] = b2d[ob + i];
    #pragma unroll 4
    for (int kb = 0; kb < 32; ++kb) {
        float4 v4 = hr[kb];
        #pragma unroll
        for (int j = 0; j < 4; ++j) {
            float v = ((const float*)&v4)[j];
            const float* wr = w2d + (kb * 4 + j) * HID + ob;
            #pragma unroll
            for (int i = 0; i < CH; ++i) a[i] = fmaf(v, wr[i], a[i]);
        }
    }
    __syncthreads();
    #pragma unroll
    for (int i4 = 0; i4 < CH / 4; ++i4) {
        float4 w4;
        #pragma unroll
        for (int j = 0; j < 4; ++j) ((float*)&w4)[j] = fmaxf(a[i4 * 4 + j], 0.f);
        hw[i4] = w4;
    }
    __syncthreads();

    // ---- P7: dec out (90) + losses; wave wv covers o in [wv*12, wv*12+12) clamped
    float labs = 0.f, lsq = 0.f;
    {
        const int o0 = wv * 12;
        float a7[12];
        #pragma unroll
        for (int i = 0; i < 12; ++i) { int oi = min(o0 + i, SIN - 1); a7[i] = bfd[oi]; }
        #pragma unroll 4
        for (int kb = 0; kb < 32; ++kb) {
            float4 v4 = hr[kb];
            #pragma unroll
            for (int j = 0; j < 4; ++j) {
                float v = ((const float*)&v4)[j];
                const float* wr = wfd + (kb * 4 + j) * SIN;
                #pragma unroll
                for (int i = 0; i < 12; ++i) {
                    int oi = min(o0 + i, SIN - 1);
                    a7[i] = fmaf(v, wr[oi], a7[i]);
                }
            }
        }
        const float* xr = x + s_glob * SIN;
        #pragma unroll
        for (int i = 0; i < 12; ++i) {
            int o = o0 + i;
            if (o < SIN) {
                float e = a7[i] - xr[o];
                labs += fabsf(e);
                lsq  = fmaf(e, e, lsq);
            }
        }
    }
    #pragma unroll
    for (int off = 32; off > 0; off >>= 1) {
        labs += __shfl_down(labs, off);
        lsq  += __shfl_down(lsq, off);
    }
    if (lane == 0) { red[wv] = labs; red[8 + wv] = lsq; }
    __syncthreads();
    if (t == 0) {
        float A1 = 0.f, S1 = 0.f;
        #pragma unroll
        for (int w = 0; w < 8; ++w) { A1 += red[w]; S1 += red[8 + w]; }
        atomicAdd(acc + 1, (double)A1);
        atomicAdd(acc + 2, (double)S1);
    }
}

__global__ void k_fin(const double* __restrict__ acc, float* __restrict__ out, int Bn) {
    if (threadIdx.x == 0 && blockIdx.x == 0) {
        double vq = acc[0] / ((double)Bn * (double)DLAT);
        double el = acc[1] / ((double)Bn * (double)SIN);
        double rc = acc[2] / ((double)Bn * (double)SIN);
        long co = 1 + (long)Bn * 4;
        out[0]      = (float)(el + 5.0 * vq);   // loss = encoder_loss*1 + vq_loss*5
        out[co]     = (float)vq;
        out[co + 1] = (float)rc;
        out[co + 2] = (float)el;
    }
}

extern "C" void kernel_launch(void* const* d_in, const int* in_sizes, int n_in,
                              void* d_out, int out_size, void* d_ws, size_t ws_size,
                              hipStream_t stream) {
    (void)n_in; (void)out_size; (void)ws_size;
    const float* x   = (const float*)d_in[0];
    const float* w1  = (const float*)d_in[1];
    const float* b1  = (const float*)d_in[2];
    const float* w2  = (const float*)d_in[3];
    const float* b2  = (const float*)d_in[4];
    const float* wf  = (const float*)d_in[5];
    const float* bf  = (const float*)d_in[6];
    const float* w1d = (const float*)d_in[7];
    const float* b1d = (const float*)d_in[8];
    const float* w2d = (const float*)d_in[9];
    const float* b2d = (const float*)d_in[10];
    const float* wfd = (const float*)d_in[11];
    const float* bfd = (const float*)d_in[12];
    const float* cb  = (const float*)d_in[13];

    float* out  = (float*)d_out;
    double* acc = (double*)d_ws;
    float* pre  = (float*)d_ws + 16;   // 64B offset, keeps doubles aligned

    int Bn = in_sizes[0] / SIN;

    hipLaunchKernelGGL(k_pre, dim3((PRE_N + 255) / 256), dim3(256), 0, stream,
                       wf, bf, w1d, cb, pre, acc);
    hipLaunchKernelGGL(k_main, dim3(Bn / 64), dim3(512), 0, stream,
                       x, w1, b1, w2, b2, b1d, w2d, b2d, wfd, bfd, pre, out, acc, Bn);
    hipLaunchKernelGGL(k_fin, dim3(1), dim3(64), 0, stream, acc, out, Bn);
}

// Round 4
// 511.075 us; speedup vs baseline: 1.3652x; 1.0067x over previous
//
#include <hip/hip_runtime.h>

// VQ-VAE fused forward, f32 throughout.
// Algebra: all 512-dim contractions folded into precomputed tables:
//   WC[k][c]  = enc_wf[k,:]·cb[c,:]          (P = rep·cb^T = h2@WC + bfc)
//   Gm[o][k]  = enc_wf[o,:]·enc_wf[k,:]      (||rep||^2 = h2^T Gm h2 + 2 u·h2 + bb)
//   Mdec[r][j]= cb[r,:]·dec_w1[:,j]          (dec h1 preact = b1d + sum_g Mdec[g*32+k_g])
//   Gram[ga,gb,ka,kb] = cb_ga[ka,:]·cb_gb[kb,:]  (residual dots across groups)
// R4: R3's spill fix. 1024-thread blocks, 16 waves x CH=8 dims -> worst-phase
// live state a[8]+tq[8]=16 floats, fits 64-VGPR/8-wave-per-SIMD budget without
// scratch (R3's (512,8) + CH=16 spilled: VGPR=32, WRITE_SIZE 114MB).
// Single in-place LDS buffer H[64][132] (37KB): 2 blk/CU * 16 waves = 32/CU.

#define SIN  90
#define HID  128
#define DLAT 512
#define NC   128
#define HST  132    // H row stride (dwords): %4==0 (b128 align), %32==4 (bank spread)

// ws float layout, after 8 doubles (64 bytes) of accumulators:
//   [0,16384)      WC
//   [16384,32768)  Gm
//   [32768,49152)  Mdec  (row = g*32+k, col j)
//   [49152,65536)  Gram  idx = ((ga*4+gb)*32+ka)*32+kb
//   [65536,65664)  cbn2[128]
//   [65664,65792)  u[128]      (wf·bf)
//   [65792,65920)  bfc[128]    (bf·cb_c)
//   [65920]        bb = ||bf||^2
#define PRE_N 65921

__device__ __forceinline__ float dot512(const float* __restrict__ a,
                                        const float* __restrict__ b) {
    const float4* a4 = (const float4*)a;
    const float4* b4 = (const float4*)b;
    float s = 0.f;
    for (int d = 0; d < DLAT / 4; ++d) {
        float4 av = a4[d], bv = b4[d];
        s = fmaf(av.x, bv.x, s);
        s = fmaf(av.y, bv.y, s);
        s = fmaf(av.z, bv.z, s);
        s = fmaf(av.w, bv.w, s);
    }
    return s;
}

__global__ void k_pre(const float* __restrict__ wf, const float* __restrict__ bf,
                      const float* __restrict__ w1d, const float* __restrict__ cb,
                      float* __restrict__ P, double* __restrict__ acc) {
    int idx = blockIdx.x * 256 + threadIdx.x;
    if (idx < 4) acc[idx] = 0.0;          // folded k_zero
    if (idx >= PRE_N) return;
    float s = 0.f;
    if (idx < 16384) {
        int k = idx >> 7, c = idx & 127;
        s = dot512(wf + k * DLAT, cb + c * DLAT);
    } else if (idx < 32768) {
        int r = idx - 16384; int o = r >> 7, k = r & 127;
        s = dot512(wf + o * DLAT, wf + k * DLAT);
    } else if (idx < 49152) {
        int r = idx - 32768; int row = r >> 7, j = r & 127;
        const float* a = cb + row * DLAT;
        for (int d = 0; d < DLAT; ++d) s = fmaf(a[d], w1d[d * HID + j], s);
    } else if (idx < 65536) {
        int r = idx - 49152;
        int kb = r & 31, ka = (r >> 5) & 31, gb = (r >> 10) & 3, ga = (r >> 12) & 3;
        s = dot512(cb + (ga * 32 + ka) * DLAT, cb + (gb * 32 + kb) * DLAT);
    } else if (idx < 65664) {
        int c = idx - 65536;
        s = dot512(cb + c * DLAT, cb + c * DLAT);
    } else if (idx < 65792) {
        int k = idx - 65664;
        s = dot512(wf + k * DLAT, bf);
    } else if (idx < 65920) {
        int c = idx - 65792;
        s = dot512(bf, cb + c * DLAT);
    } else {
        s = dot512(bf, bf);
    }
    P[idx] = s;
}

#define CH 8      // out dims per wave (16 waves x 8 = 128)
#define NW 16     // waves per block

__global__ __launch_bounds__(1024, 8) void k_main(
    const float* __restrict__ x,
    const float* __restrict__ w1, const float* __restrict__ b1,
    const float* __restrict__ w2, const float* __restrict__ b2,
    const float* __restrict__ b1d,
    const float* __restrict__ w2d, const float* __restrict__ b2d,
    const float* __restrict__ wfd, const float* __restrict__ bfd,
    const float* __restrict__ pre,
    float* __restrict__ out, double* __restrict__ acc, int Bn)
{
    __shared__ __align__(16) float H[64 * HST];
    __shared__ float qfb[NW * 64];
    __shared__ int   cbuf[4 * 64];
    __shared__ float red[2 * NW];

    const int t = threadIdx.x;
    const int lane = t & 63;
    const int wv = t >> 6;                                    // 0..15
    const int ob = __builtin_amdgcn_readfirstlane(wv) * CH;   // wave-uniform chunk base
    const long s_glob = (long)blockIdx.x * 64 + lane;

    const float* WC   = pre;
    const float* Gm   = pre + 16384;
    const float* Mdec = pre + 32768;
    const float* Gram = pre + 49152;
    const float* cbn2 = pre + 65536;
    const float* uu   = pre + 65664;
    const float* bfc  = pre + 65792;
    const float  bb   = pre[65920];

    const float4* hr = (const float4*)(H + lane * HST);   // own row, b128 stream
    float4*       hw = (float4*)(H + lane * HST + ob);    // own row, own chunk

    float a[CH];

    // ---- P0: stage x tile -> H[s][0..89] (coalesced global reads)
    {
        const float* xb = x + (long)blockIdx.x * 64 * SIN;
        for (int i = t; i < 64 * SIN; i += 1024) {
            int s = i / SIN;
            int k = i - s * SIN;
            H[s * HST + k] = xb[i];
        }
    }
    __syncthreads();

    // ---- P1: enc h1 = relu(x@w1 + b1); read own row (x), write own chunk
    #pragma unroll
    for (int i = 0; i < CH; ++i) a[i] = b1[ob + i];
    #pragma unroll 4
    for (int kb = 0; kb < 22; ++kb) {
        float4 v4 = hr[kb];
        #pragma unroll
        for (int j = 0; j < 4; ++j) {
            float v = ((const float*)&v4)[j];
            const float* wr = w1 + (kb * 4 + j) * HID + ob;
            #pragma unroll
            for (int i = 0; i < CH; ++i) a[i] = fmaf(v, wr[i], a[i]);
        }
    }
    #pragma unroll
    for (int k = 88; k < SIN; ++k) {
        float v = H[lane * HST + k];
        const float* wr = w1 + k * HID + ob;
        #pragma unroll
        for (int i = 0; i < CH; ++i) a[i] = fmaf(v, wr[i], a[i]);
    }
    __syncthreads();                      // all x reads done
    #pragma unroll
    for (int i4 = 0; i4 < CH / 4; ++i4) {
        float4 w4;
        #pragma unroll
        for (int j = 0; j < 4; ++j) ((float*)&w4)[j] = fmaxf(a[i4 * 4 + j], 0.f);
        hw[i4] = w4;
    }
    __syncthreads();

    // ---- P2: enc h2 = relu(h1@w2 + b2)
    #pragma unroll
    for (int i = 0; i < CH; ++i) a[i] = b2[ob + i];
    #pragma unroll 4
    for (int kb = 0; kb < 32; ++kb) {
        float4 v4 = hr[kb];
        #pragma unroll
        for (int j = 0; j < 4; ++j) {
            float v = ((const float*)&v4)[j];
            const float* wr = w2 + (kb * 4 + j) * HID + ob;
            #pragma unroll
            for (int i = 0; i < CH; ++i) a[i] = fmaf(v, wr[i], a[i]);
        }
    }
    __syncthreads();
    #pragma unroll
    for (int i4 = 0; i4 < CH / 4; ++i4) {
        float4 w4;
        #pragma unroll
        for (int j = 0; j < 4; ++j) ((float*)&w4)[j] = fmaxf(a[i4 * 4 + j], 0.f);
        hw[i4] = w4;
    }
    __syncthreads();

    // ---- P3 (fused): P = h2@WC + bfc; tq = Gm@h2 for ||rep||^2 partial
    {
        float tq[CH];
        #pragma unroll
        for (int i = 0; i < CH; ++i) { a[i] = bfc[ob + i]; tq[i] = 0.f; }
        #pragma unroll 4
        for (int kb = 0; kb < 32; ++kb) {
            float4 v4 = hr[kb];
            #pragma unroll
            for (int j = 0; j < 4; ++j) {
                float v = ((const float*)&v4)[j];
                const float* wr = WC + (kb * 4 + j) * NC + ob;
                const float* gr = Gm + (kb * 4 + j) * NC + ob;
                #pragma unroll
                for (int i = 0; i < CH; ++i) {
                    a[i]  = fmaf(v, wr[i], a[i]);
                    tq[i] = fmaf(v, gr[i], tq[i]);
                }
            }
        }
        // own h2 chunk for the quadratic-form partial
        float part = 0.f;
        #pragma unroll
        for (int i4 = 0; i4 < CH / 4; ++i4) {
            float4 h4 = hr[ob / 4 + i4];
            #pragma unroll
            for (int j = 0; j < 4; ++j) {
                int i = i4 * 4 + j;
                part = fmaf(tq[i] + 2.f * uu[ob + i], ((const float*)&h4)[j], part);
            }
        }
        qfb[wv * 64 + lane] = part;
        __syncthreads();                  // all h2 reads done
        #pragma unroll
        for (int i4 = 0; i4 < CH / 4; ++i4) {
            float4 w4;
            #pragma unroll
            for (int j = 0; j < 4; ++j) ((float*)&w4)[j] = a[i4 * 4 + j];
            hw[i4] = w4;
        }
    }
    __syncthreads();

    // ---- P4: residual-VQ scoring (wave 0, lane = sample; row = P[c])
    if (wv == 0) {
        float R = bb;
        #pragma unroll
        for (int w = 0; w < NW; ++w) R += qfb[w * 64 + lane];
        float vqp = 0.f;
        int c0, c1, c2, c3;
        float best, rcb, rc, sc;
        int kb;

        // group 0: score = ||c||^2 - 2 rep·c
        best = 1e30f; kb = 0; rcb = 0.f;
        #pragma unroll
        for (int cq = 0; cq < 8; ++cq) {
            float4 p4 = hr[cq];
            #pragma unroll
            for (int j = 0; j < 4; ++j) {
                int cc = cq * 4 + j;
                rc = ((const float*)&p4)[j];
                sc = cbn2[cc] - 2.f * rc;
                if (sc < best) { best = sc; kb = cc; rcb = rc; }
            }
        }
        c0 = kb;
        { float dlt = cbn2[kb] - 2.f * rcb; vqp += R + dlt; R += dlt; }

        // group 1
        best = 1e30f; kb = 0; rcb = 0.f;
        {
            const float4* gr01 = (const float4*)(Gram + ((0 * 4 + 1) * 32 + c0) * 32);
            #pragma unroll
            for (int cq = 0; cq < 8; ++cq) {
                float4 p4 = hr[8 + cq];
                float4 g4 = gr01[cq];
                #pragma unroll
                for (int j = 0; j < 4; ++j) {
                    int cc = cq * 4 + j;
                    rc = ((const float*)&p4)[j] - ((const float*)&g4)[j];
                    sc = cbn2[32 + cc] - 2.f * rc;
                    if (sc < best) { best = sc; kb = cc; rcb = rc; }
                }
            }
        }
        c1 = kb;
        { float dlt = cbn2[32 + kb] - 2.f * rcb; vqp += R + dlt; R += dlt; }

        // group 2
        best = 1e30f; kb = 0; rcb = 0.f;
        {
            const float4* gr02 = (const float4*)(Gram + ((0 * 4 + 2) * 32 + c0) * 32);
            const float4* gr12 = (const float4*)(Gram + ((1 * 4 + 2) * 32 + c1) * 32);
            #pragma unroll
            for (int cq = 0; cq < 8; ++cq) {
                float4 p4 = hr[16 + cq];
                float4 g04 = gr02[cq];
                float4 g14 = gr12[cq];
                #pragma unroll
                for (int j = 0; j < 4; ++j) {
                    int cc = cq * 4 + j;
                    rc = ((const float*)&p4)[j] - ((const float*)&g04)[j] - ((const float*)&g14)[j];
                    sc = cbn2[64 + cc] - 2.f * rc;
                    if (sc < best) { best = sc; kb = cc; rcb = rc; }
                }
            }
        }
        c2 = kb;
        { float dlt = cbn2[64 + kb] - 2.f * rcb; vqp += R + dlt; R += dlt; }

        // group 3
        best = 1e30f; kb = 0; rcb = 0.f;
        {
            const float4* gr03 = (const float4*)(Gram + ((0 * 4 + 3) * 32 + c0) * 32);
            const float4* gr13 = (const float4*)(Gram + ((1 * 4 + 3) * 32 + c1) * 32);
            const float4* gr23 = (const float4*)(Gram + ((2 * 4 + 3) * 32 + c2) * 32);
            #pragma unroll
            for (int cq = 0; cq < 8; ++cq) {
                float4 p4 = hr[24 + cq];
                float4 g04 = gr03[cq];
                float4 g14 = gr13[cq];
                float4 g24 = gr23[cq];
                #pragma unroll
                for (int j = 0; j < 4; ++j) {
                    int cc = cq * 4 + j;
                    rc = ((const float*)&p4)[j] - ((const float*)&g04)[j]
                       - ((const float*)&g14)[j] - ((const float*)&g24)[j];
                    sc = cbn2[96 + cc] - 2.f * rc;
                    if (sc < best) { best = sc; kb = cc; rcb = rc; }
                }
            }
        }
        c3 = kb;
        { float dlt = cbn2[96 + kb] - 2.f * rcb; vqp += dlt + R; }

        cbuf[0 * 64 + lane] = c0; cbuf[1 * 64 + lane] = c1;
        cbuf[2 * 64 + lane] = c2; cbuf[3 * 64 + lane] = c3;
        float* op = out + 1 + s_glob * 4;
        op[0] = (float)c0; op[1] = (float)c1; op[2] = (float)c2; op[3] = (float)c3;

        float vs = vqp;
        #pragma unroll
        for (int off = 32; off > 0; off >>= 1) vs += __shfl_down(vs, off);
        if (lane == 0) atomicAdd(acc + 0, (double)vs);
    }
    __syncthreads();                      // wave0 P reads done

    // ---- P5: dec h1 = relu(b1d + sum_g Mdec[g*32+k_g]); write own chunk
    {
        int cc0 = cbuf[lane], cc1 = cbuf[64 + lane], cc2 = cbuf[128 + lane], cc3 = cbuf[192 + lane];
        const float4* m0 = (const float4*)(Mdec + (0 * 32 + cc0) * HID + ob);
        const float4* m1 = (const float4*)(Mdec + (1 * 32 + cc1) * HID + ob);
        const float4* m2 = (const float4*)(Mdec + (2 * 32 + cc2) * HID + ob);
        const float4* m3 = (const float4*)(Mdec + (3 * 32 + cc3) * HID + ob);
        const float4* bd = (const float4*)(b1d + ob);
        #pragma unroll
        for (int i4 = 0; i4 < CH / 4; ++i4) {
            float4 v0 = m0[i4], v1 = m1[i4], v2 = m2[i4], v3 = m3[i4], vb = bd[i4];
            float4 w4;
            #pragma unroll
            for (int j = 0; j < 4; ++j) {
                float v = ((const float*)&vb)[j] + ((const float*)&v0)[j] + ((const float*)&v1)[j]
                        + ((const float*)&v2)[j] + ((const float*)&v3)[j];
                ((float*)&w4)[j] = fmaxf(v, 0.f);
            }
            hw[i4] = w4;
        }
    }
    __syncthreads();

    // ---- P6: dec h2 = relu(h@w2d + b2d)
    #pragma unroll
    for (int i = 0; i < CH; ++i) a[i] = b2d[ob + i];
    #pragma unroll 4
    for (int kb = 0; kb < 32; ++kb) {
        float4 v4 = hr[kb];
        #pragma unroll
        for (int j = 0; j < 4; ++j) {
            float v = ((const float*)&v4)[j];
            const float* wr = w2d + (kb * 4 + j) * HID + ob;
            #pragma unroll
            for (int i = 0; i < CH; ++i) a[i] = fmaf(v, wr[i], a[i]);
        }
    }
    __syncthreads();
    #pragma unroll
    for (int i4 = 0; i4 < CH / 4; ++i4) {
        float4 w4;
        #pragma unroll
        for (int j = 0; j < 4; ++j) ((float*)&w4)[j] = fmaxf(a[i4 * 4 + j], 0.f);
        hw[i4] = w4;
    }
    __syncthreads();

    // ---- P7: dec out (90) + losses; wave wv covers o in [wv*6, wv*6+6) clamped
    float labs = 0.f, lsq = 0.f;
    {
        const int o0 = wv * 6;
        float a7[6];
        #pragma unroll
        for (int i = 0; i < 6; ++i) { int oi = min(o0 + i, SIN - 1); a7[i] = bfd[oi]; }
        #pragma unroll 4
        for (int kb = 0; kb < 32; ++kb) {
            float4 v4 = hr[kb];
            #pragma unroll
            for (int j = 0; j < 4; ++j) {
                float v = ((const float*)&v4)[j];
                const float* wr = wfd + (kb * 4 + j) * SIN;
                #pragma unroll
                for (int i = 0; i < 6; ++i) {
                    int oi = min(o0 + i, SIN - 1);
                    a7[i] = fmaf(v, wr[oi], a7[i]);
                }
            }
        }
        const float* xr = x + s_glob * SIN;
        #pragma unroll
        for (int i = 0; i < 6; ++i) {
            int o = o0 + i;
            if (o < SIN) {
                float e = a7[i] - xr[o];
                labs += fabsf(e);
                lsq  = fmaf(e, e, lsq);
            }
        }
    }
    #pragma unroll
    for (int off = 32; off > 0; off >>= 1) {
        labs += __shfl_down(labs, off);
        lsq  += __shfl_down(lsq, off);
    }
    if (lane == 0) { red[wv] = labs; red[NW + wv] = lsq; }
    __syncthreads();
    if (t == 0) {
        float A1 = 0.f, S1 = 0.f;
        #pragma unroll
        for (int w = 0; w < NW; ++w) { A1 += red[w]; S1 += red[NW + w]; }
        atomicAdd(acc + 1, (double)A1);
        atomicAdd(acc + 2, (double)S1);
    }
}

__global__ void k_fin(const double* __restrict__ acc, float* __restrict__ out, int Bn) {
    if (threadIdx.x == 0 && blockIdx.x == 0) {
        double vq = acc[0] / ((double)Bn * (double)DLAT);
        double el = acc[1] / ((double)Bn * (double)SIN);
        double rc = acc[2] / ((double)Bn * (double)SIN);
        long co = 1 + (long)Bn * 4;
        out[0]      = (float)(el + 5.0 * vq);   // loss = encoder_loss*1 + vq_loss*5
        out[co]     = (float)vq;
        out[co + 1] = (float)rc;
        out[co + 2] = (float)el;
    }
}

extern "C" void kernel_launch(void* const* d_in, const int* in_sizes, int n_in,
                              void* d_out, int out_size, void* d_ws, size_t ws_size,
                              hipStream_t stream) {
    (void)n_in; (void)out_size; (void)ws_size;
    const float* x   = (const float*)d_in[0];
    const float* w1  = (const float*)d_in[1];
    const float* b1  = (const float*)d_in[2];
    const float* w2  = (const float*)d_in[3];
    const float* b2  = (const float*)d_in[4];
    const float* wf  = (const float*)d_in[5];
    const float* bf  = (const float*)d_in[6];
    const float* w1d = (const float*)d_in[7];
    const float* b1d = (const float*)d_in[8];
    const float* w2d = (const float*)d_in[9];
    const float* b2d = (const float*)d_in[10];
    const float* wfd = (const float*)d_in[11];
    const float* bfd = (const float*)d_in[12];
    const float* cb  = (const float*)d_in[13];

    float* out  = (float*)d_out;
    double* acc = (double*)d_ws;
    float* pre  = (float*)d_ws + 16;   // 64B offset, keeps doubles aligned

    int Bn = in_sizes[0] / SIN;

    hipLaunchKernelGGL(k_pre, dim3((PRE_N + 255) / 256), dim3(256), 0, stream,
                       wf, bf, w1d, cb, pre, acc);
    hipLaunchKernelGGL(k_main, dim3(Bn / 64), dim3(1024), 0, stream,
                       x, w1, b1, w2, b2, b1d, w2d, b2d, wfd, bfd, pre, out, acc, Bn);
    hipLaunchKernelGGL(k_fin, dim3(1), dim3(64), 0, stream, acc, out, Bn);
}